// Round 5
// baseline (190.987 us; speedup 1.0000x reference)
//
#include <hip/hip_runtime.h>
#include <math.h>

// Folded model (exact algebra, per-token):
//   h      = relu(x @ G1 + b11)                      [400 MACs]
//   g      = relu(h @ P1 + x @ P2 + f2)              [800 MACs]
//   logits = g @ M2 + h @ Q1 + x @ Q2 + f3           [180 MACs]
//   out    = softmax(logits)
// Logits weights stored TRANSPOSED and c-padded to 4 (M2T/Q1T/Q2T: [20][4])
// so each loop reads one v4 per k for the logits contribution.

// d_ws layout (float offsets), 16B-aligned rows
#define OFF_G1   0      // [20][20] k-major
#define OFF_P1   400    // [20][20] m'-major
#define OFF_P2   800    // [20][20] k-major
#define OFF_M2T  1200   // [20][4]  M2T[m][c] = sum_p Wc[c][p]*W2_1[p][m]
#define OFF_Q1T  1280   // [20][4]  Q1T[k][c]
#define OFF_Q2T  1360   // [20][4]  Q2T[k][c]
#define OFF_B11  1440   // [20]
#define OFF_F2   1460   // [20]
#define OFF_F3   1480   // [3] + pad
#define NWTOT    1484

__global__ void prep_kernel(const float* __restrict__ Wv, const float* __restrict__ Wres,
                            const float* __restrict__ W1, const float* __restrict__ b1,
                            const float* __restrict__ W2, const float* __restrict__ b2,
                            const float* __restrict__ W3, const float* __restrict__ b3,
                            const float* __restrict__ Wc, const float* __restrict__ bc,
                            float* __restrict__ W) {
    __shared__ float G2[400];   // [i][m]
    __shared__ float M3[60];    // [i][c]
    __shared__ float e1[20];
    const int tid = threadIdx.x;
    // ---- phase A: layer-1 folds ----
    for (int idx = tid; idx < 480; idx += 256) {
        if (idx < 400) {
            const int i = idx / 20, m = idx % 20;
            float s = 0.f;
            for (int j = 0; j < 20; ++j)
                s = fmaf(Wv[400 + j*20 + i] + Wres[400 + i*20 + j], W1[400 + m*20 + j], s);
            G2[idx] = s;
        } else if (idx < 460) {
            const int r = idx - 400, i = r / 3, c = r % 3;
            float s = 0.f;
            for (int p = 0; p < 20; ++p)
                s = fmaf(Wc[c*20 + p], W3[400 + p*20 + i], s);
            M3[r] = s;
        } else {
            const int j = idx - 460;
            e1[j] = b2[j] + b3[j];
        }
    }
    __syncthreads();
    // ---- phase B: final folded weights → d_ws ----
    for (int idx = tid; idx < NWTOT; idx += 256) {
        float s = 0.f;
        if (idx < 400) {                       // G1[k][m]
            const int k = idx / 20, m = idx % 20;
            for (int j = 0; j < 20; ++j)
                s = fmaf(Wv[j*20 + k] + Wres[k*20 + j], W1[m*20 + j], s);
        } else if (idx < 800) {                // P1[m'][m]
            const int r = idx - 400, mp = r / 20, m = r % 20;
            for (int i = 0; i < 20; ++i)
                s = fmaf(W2[i*20 + mp], G2[i*20 + m], s);
        } else if (idx < 1200) {               // P2[k][m]
            const int r = idx - 800, k = r / 20, m = r % 20;
            for (int i = 0; i < 20; ++i)
                s = fmaf(W3[i*20 + k], G2[i*20 + m], s);
        } else if (idx < 1280) {               // M2T[m][c]
            const int r = idx - 1200, m = r / 4, c = r % 4;
            if (c < 3)
                for (int p = 0; p < 20; ++p)
                    s = fmaf(Wc[c*20 + p], W2[400 + p*20 + m], s);
        } else if (idx < 1360) {               // Q1T[k][c]
            const int r = idx - 1280, k = r / 4, c = r % 4;
            if (c < 3)
                for (int i = 0; i < 20; ++i)
                    s = fmaf(W2[i*20 + k], M3[i*3 + c], s);
        } else if (idx < 1440) {               // Q2T[k][c]
            const int r = idx - 1360, k = r / 4, c = r % 4;
            if (c < 3)
                for (int i = 0; i < 20; ++i)
                    s = fmaf(W3[i*20 + k], M3[i*3 + c], s);
        } else if (idx < 1460) {               // b11
            s = b1[idx - 1440];
        } else if (idx < 1480) {               // f2
            const int m = idx - 1460;
            s = b1[20 + m];
            for (int i = 0; i < 20; ++i)
                s = fmaf(e1[i], G2[i*20 + m], s);
        } else {                               // f3 (+1 pad = 0)
            const int c = idx - 1480;
            if (c < 3) {
                s = bc[c];
                for (int p = 0; p < 20; ++p)
                    s = fmaf(Wc[c*20 + p], b2[20 + p] + b3[20 + p], s);
                for (int i = 0; i < 20; ++i)
                    s = fmaf(e1[i], M3[i*3 + c], s);
            }
        }
        W[idx] = s;
    }
}

// T=2, chunked-x, early-logits, SMEM weights, __launch_bounds__(256,2).
// 5-round lesson: hipcc splits the unified VGPR file ~50/50 arch/AGPR for
// non-MFMA kernels — arch grant ≈ cap/2 (r3: (256,2)->128 arch; r1:
// (256,3)->68; r4: (256,6)->32). Overflowing the arch grant parks state in
// AGPRs via v_accvgpr shuffles => the persistent ~2x VALU inflation and the
// 55us wall. So: cap 256 (grant 128) and keep peak live state ~114 floats
// (h[2][20]+g[2][20]+la[2][3]+x-chunks+temps) under the 128 grant.
// T=2 also halves per-token scalar weight traffic (each s_load 16B row
// feeds 8 FMAs), bringing K$ fetch (~65k cyc/CU) to parity with the true
// VALU floor (~46k cyc/CU). q-loop kept rolled so x stays chunk-wise dead.
typedef float v4f __attribute__((ext_vector_type(4)));
typedef const __attribute__((address_space(4))) v4f  c4f_t;
typedef const __attribute__((address_space(4))) float cfl_t;

__global__ __launch_bounds__(256, 2) void fwd_kernel(const float* __restrict__ X,
                                                     const float* __restrict__ Wg,
                                                     float* __restrict__ out, int npair) {
    c4f_t* W4 = (c4f_t*)(unsigned long long)Wg;
    cfl_t* Wf = (cfl_t*)(unsigned long long)Wg;

    const int pair = blockIdx.x * blockDim.x + threadIdx.x;
    if (pair >= npair) return;
    const float4* xp = reinterpret_cast<const float4*>(X + (size_t)pair * 40);

    float h[2][20], g[2][20], la[2][3];

    // init: h = b11, g = f2, la = f3 (broadcast to both tokens)
    #pragma unroll
    for (int q = 0; q < 5; ++q) {
        const v4f b = W4[OFF_B11/4 + q];
        const v4f f = W4[OFF_F2/4 + q];
        #pragma unroll
        for (int j = 0; j < 2; ++j) {
            h[j][4*q+0] = b.x; h[j][4*q+1] = b.y; h[j][4*q+2] = b.z; h[j][4*q+3] = b.w;
            g[j][4*q+0] = f.x; g[j][4*q+1] = f.y; g[j][4*q+2] = f.z; g[j][4*q+3] = f.w;
        }
    }
    {
        const float f0 = Wf[OFF_F3+0], f1 = Wf[OFF_F3+1], f2v = Wf[OFF_F3+2];
        #pragma unroll
        for (int j = 0; j < 2; ++j) { la[j][0] = f0; la[j][1] = f1; la[j][2] = f2v; }
    }

    // ---- loop1 (rolled over q): h += x@G1 ; g += x@P2 ; la += x@Q2T ----
    // x consumed 2x4 elements per iteration, dead afterwards.
    #pragma unroll 1
    for (int q = 0; q < 5; ++q) {
        const float4 va = xp[q];
        const float4 vb = xp[5 + q];
        float xc[2][4];
        xc[0][0] = va.x; xc[0][1] = va.y; xc[0][2] = va.z; xc[0][3] = va.w;
        xc[1][0] = vb.x; xc[1][1] = vb.y; xc[1][2] = vb.z; xc[1][3] = vb.w;
        #pragma unroll
        for (int d = 0; d < 4; ++d) {
            const int k = 4*q + d;
            const v4f wq2 = W4[OFF_Q2T/4 + k];
            #pragma unroll
            for (int j = 0; j < 2; ++j) {
                la[j][0] = fmaf(xc[j][d], wq2.x, la[j][0]);
                la[j][1] = fmaf(xc[j][d], wq2.y, la[j][1]);
                la[j][2] = fmaf(xc[j][d], wq2.z, la[j][2]);
            }
            #pragma unroll
            for (int r = 0; r < 5; ++r) {
                const v4f wg = W4[OFF_G1/4 + k*5 + r];
                #pragma unroll
                for (int j = 0; j < 2; ++j) {
                    h[j][4*r+0] = fmaf(xc[j][d], wg.x, h[j][4*r+0]);
                    h[j][4*r+1] = fmaf(xc[j][d], wg.y, h[j][4*r+1]);
                    h[j][4*r+2] = fmaf(xc[j][d], wg.z, h[j][4*r+2]);
                    h[j][4*r+3] = fmaf(xc[j][d], wg.w, h[j][4*r+3]);
                }
            }
            #pragma unroll
            for (int r = 0; r < 5; ++r) {
                const v4f wp = W4[OFF_P2/4 + k*5 + r];
                #pragma unroll
                for (int j = 0; j < 2; ++j) {
                    g[j][4*r+0] = fmaf(xc[j][d], wp.x, g[j][4*r+0]);
                    g[j][4*r+1] = fmaf(xc[j][d], wp.y, g[j][4*r+1]);
                    g[j][4*r+2] = fmaf(xc[j][d], wp.z, g[j][4*r+2]);
                    g[j][4*r+3] = fmaf(xc[j][d], wp.w, g[j][4*r+3]);
                }
            }
        }
    }

    // relu h
    #pragma unroll
    for (int j = 0; j < 2; ++j)
        #pragma unroll
        for (int i = 0; i < 20; ++i) h[j][i] = fmaxf(h[j][i], 0.f);

    // ---- loop2 (fully unrolled): g += h@P1 ; la += h@Q1T ----
    #pragma unroll
    for (int k = 0; k < 20; ++k) {
        const v4f wq1 = W4[OFF_Q1T/4 + k];
        #pragma unroll
        for (int j = 0; j < 2; ++j) {
            la[j][0] = fmaf(h[j][k], wq1.x, la[j][0]);
            la[j][1] = fmaf(h[j][k], wq1.y, la[j][1]);
            la[j][2] = fmaf(h[j][k], wq1.z, la[j][2]);
        }
        #pragma unroll
        for (int r = 0; r < 5; ++r) {
            const v4f wp = W4[OFF_P1/4 + k*5 + r];
            #pragma unroll
            for (int j = 0; j < 2; ++j) {
                g[j][4*r+0] = fmaf(h[j][k], wp.x, g[j][4*r+0]);
                g[j][4*r+1] = fmaf(h[j][k], wp.y, g[j][4*r+1]);
                g[j][4*r+2] = fmaf(h[j][k], wp.z, g[j][4*r+2]);
                g[j][4*r+3] = fmaf(h[j][k], wp.w, g[j][4*r+3]);
            }
        }
    }

    // relu g
    #pragma unroll
    for (int j = 0; j < 2; ++j)
        #pragma unroll
        for (int i = 0; i < 20; ++i) g[j][i] = fmaxf(g[j][i], 0.f);

    // ---- loop3 (fully unrolled): la += g@M2T ----
    #pragma unroll
    for (int k = 0; k < 20; ++k) {
        const v4f wm = W4[OFF_M2T/4 + k];
        #pragma unroll
        for (int j = 0; j < 2; ++j) {
            la[j][0] = fmaf(g[j][k], wm.x, la[j][0]);
            la[j][1] = fmaf(g[j][k], wm.y, la[j][1]);
            la[j][2] = fmaf(g[j][k], wm.z, la[j][2]);
        }
    }

    // softmax per token + store (2 tokens x 3 probs = 6 floats, 8B-aligned)
    float p[6];
    #pragma unroll
    for (int j = 0; j < 2; ++j) {
        const float m = fmaxf(fmaxf(la[j][0], la[j][1]), la[j][2]);
        const float e0 = __expf(la[j][0] - m);
        const float e1 = __expf(la[j][1] - m);
        const float e2 = __expf(la[j][2] - m);
        const float r = 1.f / (e0 + e1 + e2);
        p[3*j+0] = e0 * r; p[3*j+1] = e1 * r; p[3*j+2] = e2 * r;
    }
    float2* o2 = reinterpret_cast<float2*>(out + (size_t)pair * 6);
    o2[0] = make_float2(p[0], p[1]);
    o2[1] = make_float2(p[2], p[3]);
    o2[2] = make_float2(p[4], p[5]);
}

extern "C" void kernel_launch(void* const* d_in, const int* in_sizes, int n_in,
                              void* d_out, int out_size, void* d_ws, size_t ws_size,
                              hipStream_t stream) {
    const float* X    = (const float*)d_in[0];
    // d_in[1]=Wq, d_in[2]=Wk: dead (softmax over singleton axis == 1)
    const float* Wv   = (const float*)d_in[3];
    const float* Wres = (const float*)d_in[4];
    const float* W1   = (const float*)d_in[5];
    const float* b1   = (const float*)d_in[6];
    const float* W2   = (const float*)d_in[7];
    const float* b2   = (const float*)d_in[8];
    const float* W3   = (const float*)d_in[9];
    const float* b3   = (const float*)d_in[10];
    const float* Wc   = (const float*)d_in[11];
    const float* bc   = (const float*)d_in[12];
    float* out = (float*)d_out;
    float* W   = (float*)d_ws;

    const int S = in_sizes[0] / 20;
    const int npair = S / 2;   // S = 1048576 divides evenly

    prep_kernel<<<1, 256, 0, stream>>>(Wv, Wres, W1, b1, W2, b2, W3, b3, Wc, bc, W);

    const int block = 256;
    const int grid = (npair + block - 1) / block;
    fwd_kernel<<<grid, block, 0, stream>>>(X, W, out, npair);
}

// Round 6
// 174.789 us; speedup vs baseline: 1.0927x; 1.0927x over previous
//
#include <hip/hip_runtime.h>
#include <math.h>

// Folded model (exact algebra, per-token):
//   h      = relu(x @ G1 + b11)                      [400 MACs]
//   g      = relu(h @ P1 + x @ P2 + f2)              [800 MACs]
//   logits = g @ M2 + h @ Q1 + x @ Q2 + f3           [180 MACs]
//   out    = softmax(logits)
// Logits weights stored TRANSPOSED and c-padded to 4 (M2T/Q1T/Q2T: [20][4])
// so each loop reads one v4 per k for the logits contribution.

// d_ws layout (float offsets), 16B-aligned rows
#define OFF_G1   0      // [20][20] k-major
#define OFF_P1   400    // [20][20] m'-major
#define OFF_P2   800    // [20][20] k-major
#define OFF_M2T  1200   // [20][4]  M2T[m][c] = sum_p Wc[c][p]*W2_1[p][m]
#define OFF_Q1T  1280   // [20][4]  Q1T[k][c]
#define OFF_Q2T  1360   // [20][4]  Q2T[k][c]
#define OFF_B11  1440   // [20]
#define OFF_F2   1460   // [20]
#define OFF_F3   1480   // [3] + pad
#define NWTOT    1484

__global__ void prep_kernel(const float* __restrict__ Wv, const float* __restrict__ Wres,
                            const float* __restrict__ W1, const float* __restrict__ b1,
                            const float* __restrict__ W2, const float* __restrict__ b2,
                            const float* __restrict__ W3, const float* __restrict__ b3,
                            const float* __restrict__ Wc, const float* __restrict__ bc,
                            float* __restrict__ W) {
    __shared__ float G2[400];   // [i][m]
    __shared__ float M3[60];    // [i][c]
    __shared__ float e1[20];
    const int tid = threadIdx.x;
    // ---- phase A: layer-1 folds ----
    for (int idx = tid; idx < 480; idx += 256) {
        if (idx < 400) {
            const int i = idx / 20, m = idx % 20;
            float s = 0.f;
            for (int j = 0; j < 20; ++j)
                s = fmaf(Wv[400 + j*20 + i] + Wres[400 + i*20 + j], W1[400 + m*20 + j], s);
            G2[idx] = s;
        } else if (idx < 460) {
            const int r = idx - 400, i = r / 3, c = r % 3;
            float s = 0.f;
            for (int p = 0; p < 20; ++p)
                s = fmaf(Wc[c*20 + p], W3[400 + p*20 + i], s);
            M3[r] = s;
        } else {
            const int j = idx - 460;
            e1[j] = b2[j] + b3[j];
        }
    }
    __syncthreads();
    // ---- phase B: final folded weights → d_ws ----
    for (int idx = tid; idx < NWTOT; idx += 256) {
        float s = 0.f;
        if (idx < 400) {                       // G1[k][m]
            const int k = idx / 20, m = idx % 20;
            for (int j = 0; j < 20; ++j)
                s = fmaf(Wv[j*20 + k] + Wres[k*20 + j], W1[m*20 + j], s);
        } else if (idx < 800) {                // P1[m'][m]
            const int r = idx - 400, mp = r / 20, m = r % 20;
            for (int i = 0; i < 20; ++i)
                s = fmaf(W2[i*20 + mp], G2[i*20 + m], s);
        } else if (idx < 1200) {               // P2[k][m]
            const int r = idx - 800, k = r / 20, m = r % 20;
            for (int i = 0; i < 20; ++i)
                s = fmaf(W3[i*20 + k], G2[i*20 + m], s);
        } else if (idx < 1280) {               // M2T[m][c]
            const int r = idx - 1200, m = r / 4, c = r % 4;
            if (c < 3)
                for (int p = 0; p < 20; ++p)
                    s = fmaf(Wc[c*20 + p], W2[400 + p*20 + m], s);
        } else if (idx < 1360) {               // Q1T[k][c]
            const int r = idx - 1280, k = r / 4, c = r % 4;
            if (c < 3)
                for (int i = 0; i < 20; ++i)
                    s = fmaf(W2[i*20 + k], M3[i*3 + c], s);
        } else if (idx < 1440) {               // Q2T[k][c]
            const int r = idx - 1360, k = r / 4, c = r % 4;
            if (c < 3)
                for (int i = 0; i < 20; ++i)
                    s = fmaf(W3[i*20 + k], M3[i*3 + c], s);
        } else if (idx < 1460) {               // b11
            s = b1[idx - 1440];
        } else if (idx < 1480) {               // f2
            const int m = idx - 1460;
            s = b1[20 + m];
            for (int i = 0; i < 20; ++i)
                s = fmaf(e1[i], G2[i*20 + m], s);
        } else {                               // f3 (+1 pad = 0)
            const int c = idx - 1480;
            if (c < 3) {
                s = bc[c];
                for (int p = 0; p < 20; ++p)
                    s = fmaf(Wc[c*20 + p], b2[20 + p] + b3[20 + p], s);
                for (int i = 0; i < 20; ++i)
                    s = fmaf(e1[i], M3[i*3 + c], s);
            }
        }
        W[idx] = s;
    }
}

// T=2, fully unrolled, early-logits fusion, SMEM weights, and the decisive
// knob: amdgpu_waves_per_eu(3,3). Six datapoints show hipcc's scheduler
// always shrinks registers to chase occupancy (granted/need: 64/126, 68/126,
// 36/80, 128/320spill, 32/43, 56/114), paying ~2x VALU in accvgpr-parking +
// remat — the 55us wall. Pinning max waves/EU = min = 3 sets the VGPR
// budget to 512/3~168 AND removes any incentive to shrink below it: peak
// live here is x[40]+h[40]+g[40]+la[6]+temps ~ 140 < 168, so the natural
// code needs zero parking/remat. Occupancy 3 waves/SIMD is ample for a
// straight-line FMA stream with 40+ independent accumulator chains.
typedef float v4f __attribute__((ext_vector_type(4)));
typedef const __attribute__((address_space(4))) v4f  c4f_t;
typedef const __attribute__((address_space(4))) float cfl_t;

__global__
__attribute__((amdgpu_flat_work_group_size(256, 256)))
__attribute__((amdgpu_waves_per_eu(3, 3)))
void fwd_kernel(const float* __restrict__ X,
                const float* __restrict__ Wg,
                float* __restrict__ out, int npair) {
    c4f_t* W4 = (c4f_t*)(unsigned long long)Wg;
    cfl_t* Wf = (cfl_t*)(unsigned long long)Wg;

    const int pair = blockIdx.x * blockDim.x + threadIdx.x;
    if (pair >= npair) return;

    // load 2 tokens (40 consecutive floats) in one up-front burst
    float xa[20], xb[20];
    const float4* xp = reinterpret_cast<const float4*>(X + (size_t)pair * 40);
    #pragma unroll
    for (int q = 0; q < 5; ++q) {
        const float4 v = xp[q];
        xa[4*q+0] = v.x; xa[4*q+1] = v.y; xa[4*q+2] = v.z; xa[4*q+3] = v.w;
    }
    #pragma unroll
    for (int q = 0; q < 5; ++q) {
        const float4 v = xp[5 + q];
        xb[4*q+0] = v.x; xb[4*q+1] = v.y; xb[4*q+2] = v.z; xb[4*q+3] = v.w;
    }

    float h[2][20], g[2][20], la[2][3];

    // init: h = b11, g = f2, la = f3
    #pragma unroll
    for (int q = 0; q < 5; ++q) {
        const v4f b = W4[OFF_B11/4 + q];
        const v4f f = W4[OFF_F2/4 + q];
        #pragma unroll
        for (int j = 0; j < 2; ++j) {
            h[j][4*q+0] = b.x; h[j][4*q+1] = b.y; h[j][4*q+2] = b.z; h[j][4*q+3] = b.w;
            g[j][4*q+0] = f.x; g[j][4*q+1] = f.y; g[j][4*q+2] = f.z; g[j][4*q+3] = f.w;
        }
    }
    {
        const float f0 = Wf[OFF_F3+0], f1 = Wf[OFF_F3+1], f2v = Wf[OFF_F3+2];
        #pragma unroll
        for (int j = 0; j < 2; ++j) { la[j][0] = f0; la[j][1] = f1; la[j][2] = f2v; }
    }

    // ---- loop1 (fully unrolled): h += x@G1 ; g += x@P2 ; la += x@Q2T ----
    #pragma unroll
    for (int k = 0; k < 20; ++k) {
        const float x0 = xa[k], x1 = xb[k];
        const v4f wq2 = W4[OFF_Q2T/4 + k];
        la[0][0] = fmaf(x0, wq2.x, la[0][0]);  la[1][0] = fmaf(x1, wq2.x, la[1][0]);
        la[0][1] = fmaf(x0, wq2.y, la[0][1]);  la[1][1] = fmaf(x1, wq2.y, la[1][1]);
        la[0][2] = fmaf(x0, wq2.z, la[0][2]);  la[1][2] = fmaf(x1, wq2.z, la[1][2]);
        #pragma unroll
        for (int r = 0; r < 5; ++r) {
            const v4f wg = W4[OFF_G1/4 + k*5 + r];
            h[0][4*r+0] = fmaf(x0, wg.x, h[0][4*r+0]); h[1][4*r+0] = fmaf(x1, wg.x, h[1][4*r+0]);
            h[0][4*r+1] = fmaf(x0, wg.y, h[0][4*r+1]); h[1][4*r+1] = fmaf(x1, wg.y, h[1][4*r+1]);
            h[0][4*r+2] = fmaf(x0, wg.z, h[0][4*r+2]); h[1][4*r+2] = fmaf(x1, wg.z, h[1][4*r+2]);
            h[0][4*r+3] = fmaf(x0, wg.w, h[0][4*r+3]); h[1][4*r+3] = fmaf(x1, wg.w, h[1][4*r+3]);
        }
        #pragma unroll
        for (int r = 0; r < 5; ++r) {
            const v4f wp = W4[OFF_P2/4 + k*5 + r];
            g[0][4*r+0] = fmaf(x0, wp.x, g[0][4*r+0]); g[1][4*r+0] = fmaf(x1, wp.x, g[1][4*r+0]);
            g[0][4*r+1] = fmaf(x0, wp.y, g[0][4*r+1]); g[1][4*r+1] = fmaf(x1, wp.y, g[1][4*r+1]);
            g[0][4*r+2] = fmaf(x0, wp.z, g[0][4*r+2]); g[1][4*r+2] = fmaf(x1, wp.z, g[1][4*r+2]);
            g[0][4*r+3] = fmaf(x0, wp.w, g[0][4*r+3]); g[1][4*r+3] = fmaf(x1, wp.w, g[1][4*r+3]);
        }
    }

    // relu h
    #pragma unroll
    for (int j = 0; j < 2; ++j)
        #pragma unroll
        for (int i = 0; i < 20; ++i) h[j][i] = fmaxf(h[j][i], 0.f);

    // ---- loop2 (fully unrolled): g += h@P1 ; la += h@Q1T ----
    #pragma unroll
    for (int k = 0; k < 20; ++k) {
        const float h0 = h[0][k], h1 = h[1][k];
        const v4f wq1 = W4[OFF_Q1T/4 + k];
        la[0][0] = fmaf(h0, wq1.x, la[0][0]);  la[1][0] = fmaf(h1, wq1.x, la[1][0]);
        la[0][1] = fmaf(h0, wq1.y, la[0][1]);  la[1][1] = fmaf(h1, wq1.y, la[1][1]);
        la[0][2] = fmaf(h0, wq1.z, la[0][2]);  la[1][2] = fmaf(h1, wq1.z, la[1][2]);
        #pragma unroll
        for (int r = 0; r < 5; ++r) {
            const v4f wp = W4[OFF_P1/4 + k*5 + r];
            g[0][4*r+0] = fmaf(h0, wp.x, g[0][4*r+0]); g[1][4*r+0] = fmaf(h1, wp.x, g[1][4*r+0]);
            g[0][4*r+1] = fmaf(h0, wp.y, g[0][4*r+1]); g[1][4*r+1] = fmaf(h1, wp.y, g[1][4*r+1]);
            g[0][4*r+2] = fmaf(h0, wp.z, g[0][4*r+2]); g[1][4*r+2] = fmaf(h1, wp.z, g[1][4*r+2]);
            g[0][4*r+3] = fmaf(h0, wp.w, g[0][4*r+3]); g[1][4*r+3] = fmaf(h1, wp.w, g[1][4*r+3]);
        }
    }

    // relu g
    #pragma unroll
    for (int j = 0; j < 2; ++j)
        #pragma unroll
        for (int i = 0; i < 20; ++i) g[j][i] = fmaxf(g[j][i], 0.f);

    // ---- loop3 (fully unrolled): la += g@M2T ----
    #pragma unroll
    for (int k = 0; k < 20; ++k) {
        const float g0 = g[0][k], g1 = g[1][k];
        const v4f wm = W4[OFF_M2T/4 + k];
        la[0][0] = fmaf(g0, wm.x, la[0][0]);  la[1][0] = fmaf(g1, wm.x, la[1][0]);
        la[0][1] = fmaf(g0, wm.y, la[0][1]);  la[1][1] = fmaf(g1, wm.y, la[1][1]);
        la[0][2] = fmaf(g0, wm.z, la[0][2]);  la[1][2] = fmaf(g1, wm.z, la[1][2]);
    }

    // softmax per token + store (2 tokens x 3 probs = 6 floats, 8B-aligned)
    float p[6];
    #pragma unroll
    for (int j = 0; j < 2; ++j) {
        const float m = fmaxf(fmaxf(la[j][0], la[j][1]), la[j][2]);
        const float e0 = __expf(la[j][0] - m);
        const float e1 = __expf(la[j][1] - m);
        const float e2 = __expf(la[j][2] - m);
        const float r = 1.f / (e0 + e1 + e2);
        p[3*j+0] = e0 * r; p[3*j+1] = e1 * r; p[3*j+2] = e2 * r;
    }
    float2* o2 = reinterpret_cast<float2*>(out + (size_t)pair * 6);
    o2[0] = make_float2(p[0], p[1]);
    o2[1] = make_float2(p[2], p[3]);
    o2[2] = make_float2(p[4], p[5]);
}

extern "C" void kernel_launch(void* const* d_in, const int* in_sizes, int n_in,
                              void* d_out, int out_size, void* d_ws, size_t ws_size,
                              hipStream_t stream) {
    const float* X    = (const float*)d_in[0];
    // d_in[1]=Wq, d_in[2]=Wk: dead (softmax over singleton axis == 1)
    const float* Wv   = (const float*)d_in[3];
    const float* Wres = (const float*)d_in[4];
    const float* W1   = (const float*)d_in[5];
    const float* b1   = (const float*)d_in[6];
    const float* W2   = (const float*)d_in[7];
    const float* b2   = (const float*)d_in[8];
    const float* W3   = (const float*)d_in[9];
    const float* b3   = (const float*)d_in[10];
    const float* Wc   = (const float*)d_in[11];
    const float* bc   = (const float*)d_in[12];
    float* out = (float*)d_out;
    float* W   = (float*)d_ws;

    const int S = in_sizes[0] / 20;
    const int npair = S / 2;   // S = 1048576 divides evenly

    prep_kernel<<<1, 256, 0, stream>>>(Wv, Wres, W1, b1, W2, b2, W3, b3, Wc, bc, W);

    const int block = 256;
    const int grid = (npair + block - 1) / block;
    fwd_kernel<<<grid, block, 0, stream>>>(X, W, out, npair);
}